// Round 5
// baseline (333.958 us; speedup 1.0000x reference)
//
#include <hip/hip_runtime.h>

#define L_SEQ 2048
#define NH    16
#define HD    64
#define HDIM  1024

typedef __attribute__((ext_vector_type(8))) short  short8;
typedef __attribute__((ext_vector_type(4))) float  f32x4;

__device__ __forceinline__ unsigned short f2bf(float f) {
    unsigned int u = __float_as_uint(f);
    u += 0x7fffu + ((u >> 16) & 1u);
    return (unsigned short)(u >> 16);
}

__device__ __forceinline__ short8 ld8(const unsigned short* p) {
    return *(const short8*)p;
}

__device__ __forceinline__ void cvt16(float4 a0, float4 a1, float4 a2, float4 a3,
                                      unsigned short* dst) {
    union { short8 v; unsigned short u[8]; } w0, w1;
    w0.u[0] = f2bf(a0.x); w0.u[1] = f2bf(a0.y); w0.u[2] = f2bf(a0.z); w0.u[3] = f2bf(a0.w);
    w0.u[4] = f2bf(a1.x); w0.u[5] = f2bf(a1.y); w0.u[6] = f2bf(a1.z); w0.u[7] = f2bf(a1.w);
    w1.u[0] = f2bf(a2.x); w1.u[1] = f2bf(a2.y); w1.u[2] = f2bf(a2.z); w1.u[3] = f2bf(a2.w);
    w1.u[4] = f2bf(a3.x); w1.u[5] = f2bf(a3.y); w1.u[6] = f2bf(a3.z); w1.u[7] = f2bf(a3.w);
    *(short8*)(dst)     = w0.v;
    *(short8*)(dst + 8) = w1.v;
}

// ---- shared 128x128xK GEMM core: Y = X(row-major MxK) * W(row-major NxK)^T ----
__device__ __forceinline__ void gemm_core(const float* __restrict__ X,
                                          const float* __restrict__ W,
                                          int row0, int col0,
                                          unsigned short (*As)[40],
                                          unsigned short (*Bs)[40],
                                          f32x4 (&acc)[4][4]) {
    const int t    = threadIdx.x;
    const int lane = t & 63;
    const int wid  = t >> 6;
    const int lr   = lane & 15;
    const int lg   = lane >> 4;
    const int lk   = lg << 3;
    const int wr   = (wid >> 1) << 6;
    const int wc   = (wid & 1) << 6;
    const int srow = t >> 1;
    const int soff = (t & 1) << 4;

#pragma unroll
    for (int m = 0; m < 4; ++m)
#pragma unroll
        for (int n = 0; n < 4; ++n)
            acc[m][n] = (f32x4)0.0f;

    const float* xs = X + (size_t)(row0 + srow) * HDIM + soff;
    const float* ws = W + (size_t)(col0 + srow) * HDIM + soff;

    for (int k0 = 0; k0 < HDIM; k0 += 32) {
        const float4 a0 = *(const float4*)(xs + k0 + 0);
        const float4 a1 = *(const float4*)(xs + k0 + 4);
        const float4 a2 = *(const float4*)(xs + k0 + 8);
        const float4 a3 = *(const float4*)(xs + k0 + 12);
        const float4 b0 = *(const float4*)(ws + k0 + 0);
        const float4 b1 = *(const float4*)(ws + k0 + 4);
        const float4 b2 = *(const float4*)(ws + k0 + 8);
        const float4 b3 = *(const float4*)(ws + k0 + 12);
        __syncthreads();
        cvt16(a0, a1, a2, a3, &As[srow][soff]);
        cvt16(b0, b1, b2, b3, &Bs[srow][soff]);
        __syncthreads();
        short8 af[4], bfr[4];
#pragma unroll
        for (int m = 0; m < 4; ++m) af[m] = ld8(&As[wr + (m << 4) + lr][lk]);
#pragma unroll
        for (int n = 0; n < 4; ++n) bfr[n] = ld8(&Bs[wc + (n << 4) + lr][lk]);
#pragma unroll
        for (int m = 0; m < 4; ++m)
#pragma unroll
            for (int n = 0; n < 4; ++n)
                acc[m][n] = __builtin_amdgcn_mfma_f32_16x16x32_bf16(af[m], bfr[n], acc[m][n], 0, 0, 0);
    }
}

__global__ void cvt_pe_kernel(const float* __restrict__ src,
                              unsigned short* __restrict__ dst, int n) {
    int i = blockIdx.x * blockDim.x + threadIdx.x;
    if (i < n) dst[i] = f2bf(src[i]);
}

// Fused QKV projections. z=0: q (scaled 1/8) -> (b,h,L,d); z=1: k -> (b,h,L,d);
// z=2: v -> transposed (b,h,d,L).
__global__ __launch_bounds__(256) void qkv_kernel(
    const float* __restrict__ Xq, const float* __restrict__ Xk, const float* __restrict__ Xv,
    const float* __restrict__ Wq, const float* __restrict__ Wk, const float* __restrict__ Wv,
    const float* __restrict__ bq, const float* __restrict__ bk, const float* __restrict__ bv,
    unsigned short* __restrict__ q_ws, unsigned short* __restrict__ k_ws,
    unsigned short* __restrict__ vT_ws)
{
    __shared__ __align__(16) unsigned short As[128][40];
    __shared__ __align__(16) unsigned short Bs[128][40];

    const int z = blockIdx.z;
    const float* X  = (z == 0) ? Xq : (z == 1) ? Xk : Xv;
    const float* W  = (z == 0) ? Wq : (z == 1) ? Wk : Wv;
    const float* Bz = (z == 0) ? bq : (z == 1) ? bk : bv;

    const int row0 = blockIdx.y << 7;
    const int col0 = blockIdx.x << 7;

    f32x4 acc[4][4];
    gemm_core(X, W, row0, col0, As, Bs, acc);

    const int t = threadIdx.x;
    const int lane = t & 63;
    const int wid  = t >> 6;
    const int lr = lane & 15, lg = lane >> 4;
    const int wr = (wid >> 1) << 6, wc = (wid & 1) << 6;

    if (z <= 1) {
        const float scale = (z == 0) ? 0.125f : 1.0f;
        unsigned short* out = (z == 0) ? q_ws : k_ws;
#pragma unroll
        for (int n = 0; n < 4; ++n) {
            const int o = col0 + wc + (n << 4) + lr;
            const float bo = Bz[o];
            const int h = o >> 6, d = o & 63;
#pragma unroll
            for (int m = 0; m < 4; ++m) {
                const int ib = row0 + wr + (m << 4) + (lg << 2);
#pragma unroll
                for (int r = 0; r < 4; ++r) {
                    const int i = ib + r;
                    out[(((size_t)((i >> 11) * NH + h)) * L_SEQ + (i & (L_SEQ - 1))) * HD + d] =
                        f2bf((acc[m][n][r] + bo) * scale);
                }
            }
        }
    } else {
#pragma unroll
        for (int n = 0; n < 4; ++n) {
            const int o = col0 + wc + (n << 4) + lr;
            const float bo = Bz[o];
            const int h = o >> 6, d = o & 63;
#pragma unroll
            for (int m = 0; m < 4; ++m) {
                const int ib = row0 + wr + (m << 4) + (lg << 2);
                const int b = ib >> 11, il = ib & (L_SEQ - 1);
                ushort4 pk;
                pk.x = f2bf(acc[m][n][0] + bo);
                pk.y = f2bf(acc[m][n][1] + bo);
                pk.z = f2bf(acc[m][n][2] + bo);
                pk.w = f2bf(acc[m][n][3] + bo);
                *(ushort4*)&vT_ws[(((size_t)(b * NH + h)) * HD + d) * L_SEQ + il] = pk;
            }
        }
    }
}

// Flash attention, causal, skewed relative positional bias.
// Split-KV: block = 16 q-rows; the nt KV tiles are partitioned across the
// 4 waves (contiguous ranges); partials (O_w, m_w, l_w) merged via LDS.
// Grid = 32 bh x 128 chunks = 4096, LPT order (longest chunks first).
// LDS layout (30720 B):
//   per-wave float area  smem + wid*5376  : [16][84]  (Pq skew buf; later O/m/l partial)
//   per-wave bf16 area   smem + 21504 + wid*2304 : [16][72] (P relayout buf)
__global__ __launch_bounds__(256) void attn_kernel(
    const unsigned short* __restrict__ Q,
    const unsigned short* __restrict__ Kt,
    const unsigned short* __restrict__ VT,
    const unsigned short* __restrict__ PE,
    float* __restrict__ O)
{
    __shared__ __align__(16) char smem[30720];

    const int t    = threadIdx.x;
    const int wid  = t >> 6;
    const int lane = t & 63;
    const int lr   = lane & 15;
    const int lg   = lane >> 4;
    const int lk   = lg << 3;

    const int p     = blockIdx.x;          // 0..4095
    const int bh    = p & 31;              // XCD = p%8 -> 4 bh per XCD, L2-resident K/V
    const int chunk = 127 - (p >> 5);      // LPT: longest (most tiles) first
    const int i0    = chunk << 4;          // 16 q-rows per block
    const int nt    = (chunk >> 2) + 1;    // KV tiles covering rows i0..i0+15

    // wave's contiguous tile range [lo, lo+cnt)
    const int qd  = nt >> 2;
    const int rem = nt & 3;
    const int cnt = qd + (wid < rem ? 1 : 0);
    const int lo  = wid * qd + (wid < rem ? wid : rem);

    float (*pqw)[84]        = (float (*)[84])(smem + wid * 5376);
    unsigned short (*pw)[72] = (unsigned short (*)[72])(smem + 21504 + wid * 2304);

    const unsigned short* kbase = Kt + (size_t)bh * L_SEQ * HD;
    const unsigned short* vbase = VT + (size_t)bh * HD * L_SEQ;

    const unsigned short* qb = Q + ((size_t)bh * L_SEQ + i0 + lr) * HD + lk;
    const short8 aq0 = ld8(qb);
    const short8 aq1 = ld8(qb + 32);

    f32x4 oacc[4];
    float mrun[4], lrun[4];
#pragma unroll
    for (int r = 0; r < 4; ++r) { oacc[r] = (f32x4)0.0f; mrun[r] = -__builtin_inff(); lrun[r] = 0.0f; }

    if (cnt > 0) {
        // preload K tile lo
        short8 kf[4][2];
#pragma unroll
        for (int ct = 0; ct < 4; ++ct) {
            const unsigned short* kp = kbase + (size_t)((lo << 6) + (ct << 4) + lr) * HD + lk;
            kf[ct][0] = ld8(kp);
            kf[ct][1] = ld8(kp + 32);
        }
        // carried PE tile for first iteration (rows mlo..mlo+15)
        f32x4 pqc = (f32x4)0.0f;
        {
            const int m0 = (L_SEQ - 1) + (lo << 6) - i0 - 15;
            const unsigned short* pp = PE + (size_t)(m0 + lr) * HD + lk;
            pqc = __builtin_amdgcn_mfma_f32_16x16x32_bf16(aq0, ld8(pp), pqc, 0, 0, 0);
            pqc = __builtin_amdgcn_mfma_f32_16x16x32_bf16(aq1, ld8(pp + 32), pqc, 0, 0, 0);
        }

        for (int tt = lo; tt < lo + cnt; ++tt) {
            const int j0 = tt << 6;
            // V loads for current tile (consumed at PV; hides under softmax)
            short8 vf[4][2];
#pragma unroll
            for (int dt = 0; dt < 4; ++dt) {
                const unsigned short* vp = vbase + (size_t)((dt << 4) + lr) * L_SEQ + j0 + lk;
                vf[dt][0] = ld8(vp);
                vf[dt][1] = ld8(vp + 32);
            }

            // QK^T on prefetched K
            f32x4 s[4];
#pragma unroll
            for (int ct = 0; ct < 4; ++ct) s[ct] = (f32x4)0.0f;
#pragma unroll
            for (int ct = 0; ct < 4; ++ct) {
                s[ct] = __builtin_amdgcn_mfma_f32_16x16x32_bf16(aq0, kf[ct][0], s[ct], 0, 0, 0);
                s[ct] = __builtin_amdgcn_mfma_f32_16x16x32_bf16(aq1, kf[ct][1], s[ct], 0, 0, 0);
            }

            // prefetch next K tile
            {
                const int jn = (tt + 1 < lo + cnt) ? ((tt + 1) << 6) : j0;
#pragma unroll
                for (int ct = 0; ct < 4; ++ct) {
                    const unsigned short* kp = kbase + (size_t)(jn + (ct << 4) + lr) * HD + lk;
                    kf[ct][0] = ld8(kp);
                    kf[ct][1] = ld8(kp + 32);
                }
            }

            // relative positional bias: bias[i][j] = q_i . pe[L-1+j-i]
            const int mlo = (L_SEQ - 1) + j0 - i0 - 15;   // in [0, 2032]
            f32x4 pq[5];
            pq[0] = pqc;
#pragma unroll
            for (int pt = 1; pt < 5; ++pt) {
                f32x4 acc = (f32x4)0.0f;
                const unsigned short* pp = PE + (size_t)(mlo + (pt << 4) + lr) * HD + lk;
                acc = __builtin_amdgcn_mfma_f32_16x16x32_bf16(aq0, ld8(pp), acc, 0, 0, 0);
                acc = __builtin_amdgcn_mfma_f32_16x16x32_bf16(aq1, ld8(pp + 32), acc, 0, 0, 0);
                pq[pt] = acc;
            }
            pqc = pq[4];

#pragma unroll
            for (int pt = 0; pt < 5; ++pt)
#pragma unroll
                for (int r = 0; r < 4; ++r)
                    pqw[(lg << 2) + r][(pt << 4) + lr] = pq[pt][r];
            // skew-gather: S(r, jj) += Pq(r, jj + 15 - r)
#pragma unroll
            for (int ct = 0; ct < 4; ++ct)
#pragma unroll
                for (int r = 0; r < 4; ++r) {
                    const int rr = (lg << 2) + r;
                    s[ct][r] += pqw[rr][(ct << 4) + lr + 15 - rr];
                }
            // causal mask
#pragma unroll
            for (int ct = 0; ct < 4; ++ct)
#pragma unroll
                for (int r = 0; r < 4; ++r) {
                    const int gi = i0 + (lg << 2) + r;
                    const int gj = j0 + (ct << 4) + lr;
                    if (gj > gi) s[ct][r] = -__builtin_inff();
                }
            // online softmax
            float sc[4];
#pragma unroll
            for (int r = 0; r < 4; ++r) {
                float v = fmaxf(fmaxf(s[0][r], s[1][r]), fmaxf(s[2][r], s[3][r]));
                v = fmaxf(v, __shfl_xor(v, 1, 16));
                v = fmaxf(v, __shfl_xor(v, 2, 16));
                v = fmaxf(v, __shfl_xor(v, 4, 16));
                v = fmaxf(v, __shfl_xor(v, 8, 16));
                const float mnew = fmaxf(mrun[r], v);
                sc[r] = __expf(mrun[r] - mnew);
                mrun[r] = mnew;
            }
#pragma unroll
            for (int ct = 0; ct < 4; ++ct)
#pragma unroll
                for (int r = 0; r < 4; ++r)
                    s[ct][r] = __expf(s[ct][r] - mrun[r]);
#pragma unroll
            for (int r = 0; r < 4; ++r) {
                float sum = s[0][r] + s[1][r] + s[2][r] + s[3][r];
                sum += __shfl_xor(sum, 1, 16);
                sum += __shfl_xor(sum, 2, 16);
                sum += __shfl_xor(sum, 4, 16);
                sum += __shfl_xor(sum, 8, 16);
                lrun[r] = lrun[r] * sc[r] + sum;
            }
#pragma unroll
            for (int dt = 0; dt < 4; ++dt)
#pragma unroll
                for (int r = 0; r < 4; ++r)
                    oacc[dt][r] *= sc[r];
            // P -> LDS (bf16), reload as A-fragment layout
#pragma unroll
            for (int ct = 0; ct < 4; ++ct)
#pragma unroll
                for (int r = 0; r < 4; ++r)
                    pw[(lg << 2) + r][(ct << 4) + lr] = f2bf(s[ct][r]);
            const short8 ap0 = ld8(&pw[lr][lk]);
            const short8 ap1 = ld8(&pw[lr][32 + lk]);
#pragma unroll
            for (int dt = 0; dt < 4; ++dt) {
                oacc[dt] = __builtin_amdgcn_mfma_f32_16x16x32_bf16(ap0, vf[dt][0], oacc[dt], 0, 0, 0);
                oacc[dt] = __builtin_amdgcn_mfma_f32_16x16x32_bf16(ap1, vf[dt][1], oacc[dt], 0, 0, 0);
            }
        }
    }

    // write partial (O_w unnormalized, m_w, l_w) into this wave's float area
#pragma unroll
    for (int dt = 0; dt < 4; ++dt)
#pragma unroll
        for (int r = 0; r < 4; ++r)
            pqw[(lg << 2) + r][(dt << 4) + lr] = oacc[dt][r];
    if (lr == 0) {
#pragma unroll
        for (int r = 0; r < 4; ++r) {
            pqw[(lg << 2) + r][64] = mrun[r];
            pqw[(lg << 2) + r][65] = lrun[r];
        }
    }
    __syncthreads();

    // merge the 4 wave partials; thread t handles row (t>>4), 4 d-cols
    {
        const int r  = t >> 4;
        const int dq = t & 15;
        float mw[4];
#pragma unroll
        for (int w = 0; w < 4; ++w)
            mw[w] = ((const float*)(smem + w * 5376))[r * 84 + 64];
        float mstar = fmaxf(fmaxf(mw[0], mw[1]), fmaxf(mw[2], mw[3]));
        float4 o = make_float4(0.f, 0.f, 0.f, 0.f);
        float ls = 0.f;
#pragma unroll
        for (int w = 0; w < 4; ++w) {
            const float* pr = (const float*)(smem + w * 5376) + r * 84;
            const float wgt = __expf(mw[w] - mstar);
            const float4 ov = *(const float4*)(pr + (dq << 2));
            o.x += wgt * ov.x; o.y += wgt * ov.y; o.z += wgt * ov.z; o.w += wgt * ov.w;
            ls  += wgt * pr[65];
        }
        const float inv = 1.0f / ls;
        const int b = bh >> 4, h = bh & 15;
        float4 res = make_float4(o.x * inv, o.y * inv, o.z * inv, o.w * inv);
        *(float4*)&O[((size_t)b * L_SEQ + i0 + r) * HDIM + (h << 6) + (dq << 2)] = res;
    }
}

__global__ __launch_bounds__(256) void out_proj_kernel(
    const float* __restrict__ Xo, const float* __restrict__ Wo,
    const float* __restrict__ bo_v, float* __restrict__ Yout)
{
    __shared__ __align__(16) unsigned short As[128][40];
    __shared__ __align__(16) unsigned short Bs[128][40];

    const int row0 = blockIdx.y << 7;
    const int col0 = blockIdx.x << 7;

    f32x4 acc[4][4];
    gemm_core(Xo, Wo, row0, col0, As, Bs, acc);

    const int t = threadIdx.x;
    const int lane = t & 63;
    const int wid  = t >> 6;
    const int lr = lane & 15, lg = lane >> 4;
    const int wr = (wid >> 1) << 6, wc = (wid & 1) << 6;

#pragma unroll
    for (int n = 0; n < 4; ++n) {
        const int o = col0 + wc + (n << 4) + lr;
        const float bo = bo_v[o];
#pragma unroll
        for (int m = 0; m < 4; ++m) {
            const int ib = row0 + wr + (m << 4) + (lg << 2);
#pragma unroll
            for (int r = 0; r < 4; ++r)
                Yout[(size_t)(ib + r) * HDIM + o] = acc[m][n][r] + bo;
        }
    }
}

extern "C" void kernel_launch(void* const* d_in, const int* in_sizes, int n_in,
                              void* d_out, int out_size, void* d_ws, size_t ws_size,
                              hipStream_t stream) {
    (void)in_sizes; (void)n_in; (void)out_size;

    const float* query   = (const float*)d_in[0];
    const float* key_    = (const float*)d_in[1];
    const float* value   = (const float*)d_in[2];
    const float* Wq_w    = (const float*)d_in[3];
    const float* Wq_b    = (const float*)d_in[4];
    const float* Wk_w    = (const float*)d_in[5];
    const float* Wk_b    = (const float*)d_in[6];
    const float* Wv_w    = (const float*)d_in[7];
    const float* Wv_b    = (const float*)d_in[8];
    const float* Wo_w    = (const float*)d_in[9];
    const float* Wo_b    = (const float*)d_in[10];
    const float* pos_emb = (const float*)d_in[11];

    char* ws = (char*)d_ws;
    unsigned short* q_ws  = (unsigned short*)(ws);                              // 8 MB
    unsigned short* k_ws  = (unsigned short*)(ws + (size_t)8  * 1024 * 1024);   // 8 MB
    unsigned short* vT_ws = (unsigned short*)(ws + (size_t)16 * 1024 * 1024);   // 8 MB
    float*          O_ws  = (float*)         (ws + (size_t)24 * 1024 * 1024);   // 16 MB
    unsigned short* pe_ws = (unsigned short*)(ws + (size_t)40 * 1024 * 1024);   // 512 KB

    const int npe = (2 * L_SEQ - 1) * HD;
    if (ws_size < (size_t)40 * 1024 * 1024 + (size_t)npe * 2) return;

    cvt_pe_kernel<<<(npe + 255) / 256, 256, 0, stream>>>(pos_emb, pe_ws, npe);
    qkv_kernel<<<dim3(8, 32, 3), 256, 0, stream>>>(query, key_, value,
                                                   Wq_w, Wk_w, Wv_w,
                                                   Wq_b, Wk_b, Wv_b,
                                                   q_ws, k_ws, vT_ws);
    attn_kernel<<<dim3(4096), 256, 0, stream>>>(q_ws, k_ws, vT_ws, pe_ws, O_ws);
    out_proj_kernel<<<dim3(8, 32), 256, 0, stream>>>(O_ws, Wo_w, Wo_b, (float*)d_out);
}

// Round 6
// 317.476 us; speedup vs baseline: 1.0519x; 1.0519x over previous
//
#include <hip/hip_runtime.h>

#define L_SEQ 2048
#define NH    16
#define HD    64
#define HDIM  1024

typedef __attribute__((ext_vector_type(8))) short  short8;
typedef __attribute__((ext_vector_type(4))) float  f32x4;

__device__ __forceinline__ unsigned short f2bf(float f) {
    unsigned int u = __float_as_uint(f);
    u += 0x7fffu + ((u >> 16) & 1u);
    return (unsigned short)(u >> 16);
}

__device__ __forceinline__ short8 ld8(const unsigned short* p) {
    return *(const short8*)p;
}

// HW packed f32->bf16 (RNE): dst = {lo: bf16(a), hi: bf16(b)}
__device__ __forceinline__ unsigned int cvtpk(float a, float b) {
    unsigned int r;
    asm("v_cvt_pk_bf16_f32 %0, %1, %2" : "=v"(r) : "v"(a), "v"(b));
    return r;
}

__device__ __forceinline__ void cvt16(float4 a0, float4 a1, float4 a2, float4 a3,
                                      unsigned short* dst) {
    union { short8 v; unsigned short u[8]; } w0, w1;
    w0.u[0] = f2bf(a0.x); w0.u[1] = f2bf(a0.y); w0.u[2] = f2bf(a0.z); w0.u[3] = f2bf(a0.w);
    w0.u[4] = f2bf(a1.x); w0.u[5] = f2bf(a1.y); w0.u[6] = f2bf(a1.z); w0.u[7] = f2bf(a1.w);
    w1.u[0] = f2bf(a2.x); w1.u[1] = f2bf(a2.y); w1.u[2] = f2bf(a2.z); w1.u[3] = f2bf(a2.w);
    w1.u[4] = f2bf(a3.x); w1.u[5] = f2bf(a3.y); w1.u[6] = f2bf(a3.z); w1.u[7] = f2bf(a3.w);
    *(short8*)(dst)     = w0.v;
    *(short8*)(dst + 8) = w1.v;
}

// ---- shared 128x128xK GEMM core: Y = X(row-major MxK) * W(row-major NxK)^T ----
__device__ __forceinline__ void gemm_core(const float* __restrict__ X,
                                          const float* __restrict__ W,
                                          int row0, int col0,
                                          unsigned short (*As)[40],
                                          unsigned short (*Bs)[40],
                                          f32x4 (&acc)[4][4]) {
    const int t    = threadIdx.x;
    const int lane = t & 63;
    const int wid  = t >> 6;
    const int lr   = lane & 15;
    const int lg   = lane >> 4;
    const int lk   = lg << 3;
    const int wr   = (wid >> 1) << 6;
    const int wc   = (wid & 1) << 6;
    const int srow = t >> 1;
    const int soff = (t & 1) << 4;

#pragma unroll
    for (int m = 0; m < 4; ++m)
#pragma unroll
        for (int n = 0; n < 4; ++n)
            acc[m][n] = (f32x4)0.0f;

    const float* xs = X + (size_t)(row0 + srow) * HDIM + soff;
    const float* ws = W + (size_t)(col0 + srow) * HDIM + soff;

    for (int k0 = 0; k0 < HDIM; k0 += 32) {
        const float4 a0 = *(const float4*)(xs + k0 + 0);
        const float4 a1 = *(const float4*)(xs + k0 + 4);
        const float4 a2 = *(const float4*)(xs + k0 + 8);
        const float4 a3 = *(const float4*)(xs + k0 + 12);
        const float4 b0 = *(const float4*)(ws + k0 + 0);
        const float4 b1 = *(const float4*)(ws + k0 + 4);
        const float4 b2 = *(const float4*)(ws + k0 + 8);
        const float4 b3 = *(const float4*)(ws + k0 + 12);
        __syncthreads();
        cvt16(a0, a1, a2, a3, &As[srow][soff]);
        cvt16(b0, b1, b2, b3, &Bs[srow][soff]);
        __syncthreads();
        short8 af[4], bfr[4];
#pragma unroll
        for (int m = 0; m < 4; ++m) af[m] = ld8(&As[wr + (m << 4) + lr][lk]);
#pragma unroll
        for (int n = 0; n < 4; ++n) bfr[n] = ld8(&Bs[wc + (n << 4) + lr][lk]);
#pragma unroll
        for (int m = 0; m < 4; ++m)
#pragma unroll
            for (int n = 0; n < 4; ++n)
                acc[m][n] = __builtin_amdgcn_mfma_f32_16x16x32_bf16(af[m], bfr[n], acc[m][n], 0, 0, 0);
    }
}

__global__ void cvt_pe_kernel(const float* __restrict__ src,
                              unsigned short* __restrict__ dst, int n) {
    int i = blockIdx.x * blockDim.x + threadIdx.x;
    if (i < n) dst[i] = f2bf(src[i]);
}

// Fused QKV projections. z=0: q (scaled 1/8) -> (b,h,L,d); z=1: k -> (b,h,L,d);
// z=2: v -> transposed (b,h,d,L).
__global__ __launch_bounds__(256) void qkv_kernel(
    const float* __restrict__ Xq, const float* __restrict__ Xk, const float* __restrict__ Xv,
    const float* __restrict__ Wq, const float* __restrict__ Wk, const float* __restrict__ Wv,
    const float* __restrict__ bq, const float* __restrict__ bk, const float* __restrict__ bv,
    unsigned short* __restrict__ q_ws, unsigned short* __restrict__ k_ws,
    unsigned short* __restrict__ vT_ws)
{
    __shared__ __align__(16) unsigned short As[128][40];
    __shared__ __align__(16) unsigned short Bs[128][40];

    const int z = blockIdx.z;
    const float* X  = (z == 0) ? Xq : (z == 1) ? Xk : Xv;
    const float* W  = (z == 0) ? Wq : (z == 1) ? Wk : Wv;
    const float* Bz = (z == 0) ? bq : (z == 1) ? bk : bv;

    const int row0 = blockIdx.y << 7;
    const int col0 = blockIdx.x << 7;

    f32x4 acc[4][4];
    gemm_core(X, W, row0, col0, As, Bs, acc);

    const int t = threadIdx.x;
    const int lane = t & 63;
    const int wid  = t >> 6;
    const int lr = lane & 15, lg = lane >> 4;
    const int wr = (wid >> 1) << 6, wc = (wid & 1) << 6;

    if (z <= 1) {
        const float scale = (z == 0) ? 0.125f : 1.0f;
        unsigned short* out = (z == 0) ? q_ws : k_ws;
#pragma unroll
        for (int n = 0; n < 4; ++n) {
            const int o = col0 + wc + (n << 4) + lr;
            const float bo = Bz[o];
            const int h = o >> 6, d = o & 63;
#pragma unroll
            for (int m = 0; m < 4; ++m) {
                const int ib = row0 + wr + (m << 4) + (lg << 2);
#pragma unroll
                for (int r = 0; r < 4; ++r) {
                    const int i = ib + r;
                    out[(((size_t)((i >> 11) * NH + h)) * L_SEQ + (i & (L_SEQ - 1))) * HD + d] =
                        f2bf((acc[m][n][r] + bo) * scale);
                }
            }
        }
    } else {
#pragma unroll
        for (int n = 0; n < 4; ++n) {
            const int o = col0 + wc + (n << 4) + lr;
            const float bo = Bz[o];
            const int h = o >> 6, d = o & 63;
#pragma unroll
            for (int m = 0; m < 4; ++m) {
                const int ib = row0 + wr + (m << 4) + (lg << 2);
                const int b = ib >> 11, il = ib & (L_SEQ - 1);
                ushort4 pk;
                pk.x = f2bf(acc[m][n][0] + bo);
                pk.y = f2bf(acc[m][n][1] + bo);
                pk.z = f2bf(acc[m][n][2] + bo);
                pk.w = f2bf(acc[m][n][3] + bo);
                *(ushort4*)&vT_ws[(((size_t)(b * NH + h)) * HD + d) * L_SEQ + il] = pk;
            }
        }
    }
}

// One 16-row causal flash slice in TRANSPOSED score layout:
// S2 = mfma(K, Q): lane owns q-row qr = lane&15; kr spread over (lg, reg).
// Softmax: in-lane tree + 2 shuffles; per-lane scalar running (m, l).
// Bias: PE MFMAs in original orientation, skew folded at LDS-write time.
// P relayout for PV: cvt_pk + 16 ds_bpermute (no LDS round-trip).
__device__ __forceinline__ void attn_rowblock(
    const unsigned short* __restrict__ Q,
    const unsigned short* __restrict__ kbase,
    const unsigned short* __restrict__ vbase,
    const unsigned short* __restrict__ PE,
    float* __restrict__ O,
    int bh, int i0, int lr, int lg, int lk,
    float (*blds)[20])
{
    const unsigned short* qb = Q + ((size_t)bh * L_SEQ + i0 + lr) * HD + lk;
    const short8 aq0 = ld8(qb);
    const short8 aq1 = ld8(qb + 32);

    const int gi    = i0 + lr;
    const int idx0  = ((lg & 1) << 7) + (lr << 2);   // byte index for ds_bpermute
    const int idx1  = idx0 + 64;
    const int selhi = lg >> 1;

    f32x4 oacc[4];
#pragma unroll
    for (int dt = 0; dt < 4; ++dt) oacc[dt] = (f32x4)0.0f;
    float mrun = -__builtin_inff();
    float lrun = 0.0f;

    const int jend = i0 + 15;

    // preload K tile 0
    short8 kf[4][2];
#pragma unroll
    for (int ct = 0; ct < 4; ++ct) {
        const unsigned short* kp = kbase + (size_t)((ct << 4) + lr) * HD + lk;
        kf[ct][0] = ld8(kp);
        kf[ct][1] = ld8(kp + 32);
    }
    // carried PE tile (rows mlo..mlo+15 of the first iteration)
    f32x4 pqc = (f32x4)0.0f;
    {
        const unsigned short* pp = PE + (size_t)((L_SEQ - 1) - i0 - 15 + lr) * HD + lk;
        pqc = __builtin_amdgcn_mfma_f32_16x16x32_bf16(aq0, ld8(pp), pqc, 0, 0, 0);
        pqc = __builtin_amdgcn_mfma_f32_16x16x32_bf16(aq1, ld8(pp + 32), pqc, 0, 0, 0);
    }

    for (int j0 = 0; j0 <= jend; j0 += 64) {
        // V fragments for current tile (A-operand of PV, V^T rows)
        short8 vf[4][2];
#pragma unroll
        for (int dt = 0; dt < 4; ++dt) {
            const unsigned short* vp = vbase + (size_t)((dt << 4) + lr) * L_SEQ + j0 + lk;
            vf[dt][0] = ld8(vp);
            vf[dt][1] = ld8(vp + 32);
        }

        // transposed QK^T: S2[kr][qr], kr=(lg<<2)+reg per ct-tile, qr=lane&15
        f32x4 s2[4];
#pragma unroll
        for (int ct = 0; ct < 4; ++ct) {
            f32x4 a = (f32x4)0.0f;
            a = __builtin_amdgcn_mfma_f32_16x16x32_bf16(kf[ct][0], aq0, a, 0, 0, 0);
            a = __builtin_amdgcn_mfma_f32_16x16x32_bf16(kf[ct][1], aq1, a, 0, 0, 0);
            s2[ct] = a;
        }

        // prefetch next K tile
        {
            const int jn = (j0 + 64 <= jend) ? (j0 + 64) : j0;
#pragma unroll
            for (int ct = 0; ct < 4; ++ct) {
                const unsigned short* kp = kbase + (size_t)(jn + (ct << 4) + lr) * HD + lk;
                kf[ct][0] = ld8(kp);
                kf[ct][1] = ld8(kp + 32);
            }
        }

        // relative positional bias: bias[qr][kr] = q_qr . pe[mlo + kr + 15 - qr]
        const int mlo = (L_SEQ - 1) + j0 - i0 - 15;   // in [0, 2032]
        f32x4 pq[5];
        pq[0] = pqc;
#pragma unroll
        for (int pt = 1; pt < 5; ++pt) {
            f32x4 a = (f32x4)0.0f;
            const unsigned short* pp = PE + (size_t)(mlo + (pt << 4) + lr) * HD + lk;
            a = __builtin_amdgcn_mfma_f32_16x16x32_bf16(aq0, ld8(pp), a, 0, 0, 0);
            a = __builtin_amdgcn_mfma_f32_16x16x32_bf16(aq1, ld8(pp + 32), a, 0, 0, 0);
            pq[pt] = a;
        }
        pqc = pq[4];

        // scatter Pq with skew folded in: blds[kr = pe_c + qw - 15][qw]
        // (pt=1..3 always in range; pt=0/4 partially masked)
#pragma unroll
        for (int r = 0; r < 4; ++r) {
            const int qw = (lg << 2) + r;
            {
                const int kr = lr + qw - 15;
                if (kr >= 0) blds[kr][qw] = pq[0][r];
            }
#pragma unroll
            for (int pt = 1; pt < 4; ++pt)
                blds[(pt << 4) + lr + qw - 15][qw] = pq[pt][r];
            {
                const int kr = 49 + lr + qw;
                if (kr < 64) blds[kr][qw] = pq[4][r];
            }
        }

        // bias add + causal mask (reads land directly in transposed layout)
#pragma unroll
        for (int ct = 0; ct < 4; ++ct)
#pragma unroll
            for (int r = 0; r < 4; ++r) {
                const int krl = (ct << 4) + (lg << 2) + r;
                const float v = s2[ct][r] + blds[krl][lr];
                s2[ct][r] = (j0 + krl > gi) ? -__builtin_inff() : v;
            }

        // online softmax: per-lane row; in-lane tree + 2 cross-group shuffles
        float c0 = fmaxf(fmaxf(s2[0][0], s2[0][1]), fmaxf(s2[0][2], s2[0][3]));
        float c1 = fmaxf(fmaxf(s2[1][0], s2[1][1]), fmaxf(s2[1][2], s2[1][3]));
        float c2 = fmaxf(fmaxf(s2[2][0], s2[2][1]), fmaxf(s2[2][2], s2[2][3]));
        float c3 = fmaxf(fmaxf(s2[3][0], s2[3][1]), fmaxf(s2[3][2], s2[3][3]));
        float vmax = fmaxf(fmaxf(c0, c1), fmaxf(c2, c3));
        vmax = fmaxf(vmax, __shfl_xor(vmax, 16));
        vmax = fmaxf(vmax, __shfl_xor(vmax, 32));
        const float mnew = fmaxf(mrun, vmax);
        const float sc = __expf(mrun - mnew);
        mrun = mnew;
#pragma unroll
        for (int ct = 0; ct < 4; ++ct)
#pragma unroll
            for (int r = 0; r < 4; ++r)
                s2[ct][r] = __expf(s2[ct][r] - mnew);
        float t0 = (s2[0][0] + s2[0][1]) + (s2[0][2] + s2[0][3]);
        float t1 = (s2[1][0] + s2[1][1]) + (s2[1][2] + s2[1][3]);
        float t2 = (s2[2][0] + s2[2][1]) + (s2[2][2] + s2[2][3]);
        float t3 = (s2[3][0] + s2[3][1]) + (s2[3][2] + s2[3][3]);
        float sum = (t0 + t1) + (t2 + t3);
        sum += __shfl_xor(sum, 16);
        sum += __shfl_xor(sum, 32);
        lrun = lrun * sc + sum;
#pragma unroll
        for (int dt = 0; dt < 4; ++dt)
#pragma unroll
            for (int r = 0; r < 4; ++r)
                oacc[dt][r] *= sc;

        // P -> bf16 B-fragments via cvt_pk + ds_bpermute (in-register relayout)
        unsigned int pkl[4], pkh[4];
#pragma unroll
        for (int ct = 0; ct < 4; ++ct) {
            pkl[ct] = cvtpk(s2[ct][0], s2[ct][1]);
            pkh[ct] = cvtpk(s2[ct][2], s2[ct][3]);
        }
        union { short8 v; int u[4]; } pf0, pf1;
#pragma unroll
        for (int m = 0; m < 4; ++m) {
            const int bidx = (m & 2) ? idx1 : idx0;
            const int a0 = __builtin_amdgcn_ds_bpermute(bidx, (int)((m & 1) ? pkh[0] : pkl[0]));
            const int a1 = __builtin_amdgcn_ds_bpermute(bidx, (int)((m & 1) ? pkh[1] : pkl[1]));
            pf0.u[m] = selhi ? a1 : a0;
            const int b0 = __builtin_amdgcn_ds_bpermute(bidx, (int)((m & 1) ? pkh[2] : pkl[2]));
            const int b1 = __builtin_amdgcn_ds_bpermute(bidx, (int)((m & 1) ? pkh[3] : pkl[3]));
            pf1.u[m] = selhi ? b1 : b0;
        }

        // PV: O2[vd][qr] += V^T . P  (vf is the A-operand directly)
#pragma unroll
        for (int dt = 0; dt < 4; ++dt) {
            oacc[dt] = __builtin_amdgcn_mfma_f32_16x16x32_bf16(vf[dt][0], pf0.v, oacc[dt], 0, 0, 0);
            oacc[dt] = __builtin_amdgcn_mfma_f32_16x16x32_bf16(vf[dt][1], pf1.v, oacc[dt], 0, 0, 0);
        }
    }

    // epilogue: normalize (per-lane scalar l) and store float4 runs
    const float inv = 1.0f / lrun;
    const int b = bh >> 4, h = bh & 15;
#pragma unroll
    for (int dt = 0; dt < 4; ++dt) {
        float4 res;
        res.x = oacc[dt][0] * inv;
        res.y = oacc[dt][1] * inv;
        res.z = oacc[dt][2] * inv;
        res.w = oacc[dt][3] * inv;
        *(float4*)&O[((size_t)b * L_SEQ + i0 + lr) * HDIM + (h << 6) + (dt << 4) + (lg << 2)] = res;
    }
}

// Flash attention, causal, skewed relative positional bias (transposed-S).
// Grid 512: XCD-grouped bh (4 per XCD, K/V L2-resident); paired row-blocks
// {31-p, p} per block for balance. No inter-wave LDS sharing, no barriers.
__global__ __launch_bounds__(256) void attn_kernel(
    const unsigned short* __restrict__ Q,
    const unsigned short* __restrict__ Kt,
    const unsigned short* __restrict__ VT,
    const unsigned short* __restrict__ PE,
    float* __restrict__ O)
{
    __shared__ __align__(16) float blds_all[4][64][20];

    const int t    = threadIdx.x;
    const int wid  = t >> 6;
    const int lane = t & 63;
    const int lr   = lane & 15;
    const int lg   = lane >> 4;
    const int lk   = lg << 3;

    const int blk = blockIdx.x;
    const int xcd = blk & 7;
    const int idx = blk >> 3;
    const int bh  = ((idx & 3) << 3) | xcd;
    const int p   = idx >> 2;

    const unsigned short* kbase = Kt + (size_t)bh * L_SEQ * HD;
    const unsigned short* vbase = VT + (size_t)bh * HD * L_SEQ;

    float (*blds)[20] = blds_all[wid];

    attn_rowblock(Q, kbase, vbase, PE, O, bh, ((31 - p) << 6) + (wid << 4), lr, lg, lk, blds);
    attn_rowblock(Q, kbase, vbase, PE, O, bh, (p << 6) + (wid << 4), lr, lg, lk, blds);
}

__global__ __launch_bounds__(256) void out_proj_kernel(
    const float* __restrict__ Xo, const float* __restrict__ Wo,
    const float* __restrict__ bo_v, float* __restrict__ Yout)
{
    __shared__ __align__(16) unsigned short As[128][40];
    __shared__ __align__(16) unsigned short Bs[128][40];

    const int row0 = blockIdx.y << 7;
    const int col0 = blockIdx.x << 7;

    f32x4 acc[4][4];
    gemm_core(Xo, Wo, row0, col0, As, Bs, acc);

    const int t = threadIdx.x;
    const int lane = t & 63;
    const int wid  = t >> 6;
    const int lr = lane & 15, lg = lane >> 4;
    const int wr = (wid >> 1) << 6, wc = (wid & 1) << 6;

#pragma unroll
    for (int n = 0; n < 4; ++n) {
        const int o = col0 + wc + (n << 4) + lr;
        const float bo = bo_v[o];
#pragma unroll
        for (int m = 0; m < 4; ++m) {
            const int ib = row0 + wr + (m << 4) + (lg << 2);
#pragma unroll
            for (int r = 0; r < 4; ++r)
                Yout[(size_t)(ib + r) * HDIM + o] = acc[m][n][r] + bo;
        }
    }
}

extern "C" void kernel_launch(void* const* d_in, const int* in_sizes, int n_in,
                              void* d_out, int out_size, void* d_ws, size_t ws_size,
                              hipStream_t stream) {
    (void)in_sizes; (void)n_in; (void)out_size;

    const float* query   = (const float*)d_in[0];
    const float* key_    = (const float*)d_in[1];
    const float* value   = (const float*)d_in[2];
    const float* Wq_w    = (const float*)d_in[3];
    const float* Wq_b    = (const float*)d_in[4];
    const float* Wk_w    = (const float*)d_in[5];
    const float* Wk_b    = (const float*)d_in[6];
    const float* Wv_w    = (const float*)d_in[7];
    const float* Wv_b    = (const float*)d_in[8];
    const float* Wo_w    = (const float*)d_in[9];
    const float* Wo_b    = (const float*)d_in[10];
    const float* pos_emb = (const float*)d_in[11];

    char* ws = (char*)d_ws;
    unsigned short* q_ws  = (unsigned short*)(ws);                              // 8 MB
    unsigned short* k_ws  = (unsigned short*)(ws + (size_t)8  * 1024 * 1024);   // 8 MB
    unsigned short* vT_ws = (unsigned short*)(ws + (size_t)16 * 1024 * 1024);   // 8 MB
    float*          O_ws  = (float*)         (ws + (size_t)24 * 1024 * 1024);   // 16 MB
    unsigned short* pe_ws = (unsigned short*)(ws + (size_t)40 * 1024 * 1024);   // 512 KB

    const int npe = (2 * L_SEQ - 1) * HD;
    if (ws_size < (size_t)40 * 1024 * 1024 + (size_t)npe * 2) return;

    cvt_pe_kernel<<<(npe + 255) / 256, 256, 0, stream>>>(pos_emb, pe_ws, npe);
    qkv_kernel<<<dim3(8, 32, 3), 256, 0, stream>>>(query, key_, value,
                                                   Wq_w, Wk_w, Wv_w,
                                                   Wq_b, Wk_b, Wv_b,
                                                   q_ws, k_ws, vT_ws);
    attn_kernel<<<dim3(512), 256, 0, stream>>>(q_ws, k_ws, vT_ws, pe_ws, O_ws);
    out_proj_kernel<<<dim3(8, 32), 256, 0, stream>>>(O_ws, Wo_w, Wo_b, (float*)d_out);
}